// Round 2
// baseline (391.808 us; speedup 1.0000x reference)
//
#include <hip/hip_runtime.h>

// Cost-volume builder:
// out[b, c2, d, h, w] with shape (4, 64, 48, 64, 128) fp32
//   c2 <  32: (w >= d) ? left [b, c2,    h, w    ] : 0
//   c2 >= 32: (w >= d) ? right[b, c2-32, h, w - d] : 0
//
// Write-bound: 402.7 MB out vs 8 MB in. Harness timed region = re-poison fill
// (~255 us, 1.6 GB @ 6.3 TB/s -- also the plain-store ceiling on this box)
// + this kernel.
//
// R4 (loop inversion, 48 stores/thread): kernel ~136 us (2.95 TB/s). Left half
// near peak; right half vmcnt-serialized: its sliding-window loop loaded the
// next float4 AFTER each group's 4 stores, and loads+stores share one in-order
// vmcnt counter -> using the load drains the stores -> one store-completion
// round-trip (~800 cy) per 4 KB per wave (~2 TB/s on the right half).
//
// R5: (a) hoist ALL 13 right-half loads above ALL 48 stores -- windows for
// every d come from r[0..12] in registers (r[g]=0 past row start IS the
// (w>=d) mask), so no wait ever gates on a store. (b) plain stores instead of
// nontemporal: the fill kernel proves the plain L2 write-back path streams
// 6.3 TB/s at 10% occupancy; nt bypasses L2 write-combining and is the other
// suspect for the ~3 TB/s cap. Cache pollution risk is only the 8 MB inputs.

#define BB 4
#define CC 32
#define HH 64
#define WW 128
#define DD 48

typedef float vfloat4 __attribute__((ext_vector_type(4)));

__global__ __launch_bounds__(256) void cost_kernel(
    const float* __restrict__ left,
    const float* __restrict__ right,
    float* __restrict__ out)
{
    // grid: (H*W/4/256 = 8, 1, B*2C = 256)
    const int p  = blockIdx.x * 256 + threadIdx.x;  // float4 index within (h,w) plane
    const int bc = blockIdx.z;                      // b*64 + c2
    const int b  = bc >> 6;
    const int c2 = bc & 63;
    const int h  = p >> 5;                          // W/4 = 32 float4 per row
    const int k0 = p & 31;                          // float4 column within row
    const int w0 = k0 * 4;                          // starting w of this float4

    const bool is_right = (c2 >= CC);               // uniform per block
    const int  c        = is_right ? (c2 - CC) : c2;
    const float* __restrict__ src = is_right ? right : left;
    const vfloat4* __restrict__ row4 =
        reinterpret_cast<const vfloat4*>(src + ((((size_t)b * CC + c) * HH + h) * WW));

    const int stride4 = HH * WW / 4;                // 2048 float4 per d-slab
    vfloat4* __restrict__ out4 = reinterpret_cast<vfloat4*>(out)
                               + (size_t)bc * DD * stride4 + p;

    if (!is_right) {
        // One load, 48 stores; load is oldest vmcnt entry, stores never gate.
        const vfloat4 lv = row4[k0];
        #pragma unroll
        for (int d = 0; d < DD; ++d) {
            vfloat4 o;
            o.x = (w0 + 0 >= d) ? lv.x : 0.0f;
            o.y = (w0 + 1 >= d) ? lv.y : 0.0f;
            o.z = (w0 + 2 >= d) ? lv.z : 0.0f;
            o.w = (w0 + 3 >= d) ? lv.w : 0.0f;
            out4[(size_t)d * stride4] = o;
        }
    } else {
        // Preload every source float4 this thread will ever need (r[g] covers
        // disparity group g = d/4). r[g] = 0 once k0-g < 0 -- this reproduces
        // the (w >= d) mask exactly, no mask instructions.
        vfloat4 r[DD / 4 + 1];
        #pragma unroll
        for (int g = 0; g <= DD / 4; ++g) {
            r[g] = (vfloat4)(0.0f);
            if (k0 - g >= 0) r[g] = row4[k0 - g];
        }

        // 48 back-to-back stores, windows built purely in registers with
        // static indices (stays in VGPRs after full unroll).
        #pragma unroll
        for (int g = 0; g < DD / 4; ++g) {
            const vfloat4 b4 = r[g];
            const vfloat4 a4 = r[g + 1];

            const vfloat4 o0 = b4;
            vfloat4 o1; o1.x = a4.w; o1.y = b4.x; o1.z = b4.y; o1.w = b4.z;
            vfloat4 o2; o2.x = a4.z; o2.y = a4.w; o2.z = b4.x; o2.w = b4.y;
            vfloat4 o3; o3.x = a4.y; o3.y = a4.z; o3.z = a4.w; o3.w = b4.x;

            out4[(size_t)(4 * g + 0) * stride4] = o0;
            out4[(size_t)(4 * g + 1) * stride4] = o1;
            out4[(size_t)(4 * g + 2) * stride4] = o2;
            out4[(size_t)(4 * g + 3) * stride4] = o3;
        }
    }
}

extern "C" void kernel_launch(void* const* d_in, const int* in_sizes, int n_in,
                              void* d_out, int out_size, void* d_ws, size_t ws_size,
                              hipStream_t stream)
{
    const float* left  = (const float*)d_in[0];
    const float* right = (const float*)d_in[1];
    float* out = (float*)d_out;

    dim3 grid(HH * WW / 4 / 256, 1, BB * 2 * CC);   // (8, 1, 256)
    cost_kernel<<<grid, dim3(256), 0, stream>>>(left, right, out);
}